// Round 4
// baseline (431.625 us; speedup 1.0000x reference)
//
#include <hip/hip_runtime.h>
#include <hip/hip_bf16.h>
#include <math.h>

#define N_TOK 4096
#define D_IN  768
#define N_EXP 8
#define H_DIM 3072
#define NC    6144      // 2*H_DIM concatenated
#define NP    8192      // N_TOK * TOPK
#define BM    128
#define BK    64
#define BN2   128
#define MAXT  72        // NP/BM + N_EXP   (128-tiles, ffn2)
#define MAXT2 40        // NP/256 + N_EXP  (256-tiles, ffn1g)

typedef float f32x4 __attribute__((ext_vector_type(4)));
typedef short s16x8 __attribute__((ext_vector_type(8)));

__device__ __forceinline__ unsigned short f2bf(float f) {
    unsigned int u = __builtin_bit_cast(unsigned int, f);
    u += 0x7fffu + ((u >> 16) & 1u);
    return (unsigned short)(u >> 16);
}
__device__ __forceinline__ float bf2f(unsigned short u) {
    unsigned int x = ((unsigned int)u) << 16;
    return __builtin_bit_cast(float, x);
}

__device__ __forceinline__ void gload_lds16(const void* g, void* l) {
    __builtin_amdgcn_global_load_lds(
        (const __attribute__((address_space(1))) unsigned int*)g,
        (__attribute__((address_space(3))) unsigned int*)l, 16, 0, 0);
}

// ---- transpose + f32->bf16: src[e][R][C] -> dst[e*eStride + (rowOff+c)*R + r] ----
__global__ __launch_bounds__(256) void transpose_cvt_kernel(
    const float* __restrict__ src, unsigned short* __restrict__ dst, int R, int C,
    size_t eStride, int rowOff) {
    __shared__ float t[32][33];
    int e = blockIdx.z;
    int c0 = blockIdx.x * 32, r0 = blockIdx.y * 32;
    int tx = threadIdx.x, ty = threadIdx.y; // 32 x 8
    const float* s = src + (size_t)e * R * C;
    unsigned short* d = dst + (size_t)e * eStride;
#pragma unroll
    for (int i = 0; i < 4; i++)
        t[ty + 8 * i][tx] = s[(size_t)(r0 + ty + 8 * i) * C + c0 + tx];
    __syncthreads();
#pragma unroll
    for (int i = 0; i < 4; i++)
        d[(size_t)(rowOff + c0 + ty + 8 * i) * R + r0 + tx] = f2bf(t[tx][ty + 8 * i]);
}

// ---- router ----
__global__ __launch_bounds__(64) void router_kernel(
    const float* __restrict__ x, const float* __restrict__ rw, const float* __restrict__ rb,
    int* counts, int* top1cnt, float* probs_sum, int* tk_e, float* tk_w) {
    __shared__ __align__(16) float s_rw[D_IN * N_EXP];
    __shared__ float s_ps[N_EXP];
    __shared__ int s_cnt[N_EXP], s_t1[N_EXP];
    int tid = threadIdx.x;
    for (int i = tid; i < D_IN * N_EXP / 4; i += 64)
        ((float4*)s_rw)[i] = ((const float4*)rw)[i];
    if (tid < N_EXP) { s_ps[tid] = 0.f; s_cnt[tid] = 0; s_t1[tid] = 0; }
    __syncthreads();

    int tok = blockIdx.x * 64 + tid;
    float acc[N_EXP];
#pragma unroll
    for (int e = 0; e < N_EXP; e++) acc[e] = rb[e];
    const float* xr = x + (size_t)tok * D_IN;
    for (int d = 0; d < D_IN; d++) {
        float xv = xr[d];
#pragma unroll
        for (int e = 0; e < N_EXP; e++) acc[e] += xv * s_rw[d * N_EXP + e];
    }
    float m = acc[0];
#pragma unroll
    for (int e = 1; e < N_EXP; e++) m = fmaxf(m, acc[e]);
    float p[N_EXP], s = 0.f;
#pragma unroll
    for (int e = 0; e < N_EXP; e++) { p[e] = __expf(acc[e] - m); s += p[e]; }
    float inv = 1.f / s;
#pragma unroll
    for (int e = 0; e < N_EXP; e++) p[e] *= inv;
    int e0 = 0;
#pragma unroll
    for (int e = 1; e < N_EXP; e++) if (p[e] > p[e0]) e0 = e;
    int e1 = (e0 == 0) ? 1 : 0;
#pragma unroll
    for (int e = 0; e < N_EXP; e++) if (e != e0 && p[e] > p[e1]) e1 = e;
    float denom = 1.f / (p[e0] + p[e1]);
    tk_e[tok * 2] = e0; tk_e[tok * 2 + 1] = e1;
    tk_w[tok * 2] = p[e0] * denom; tk_w[tok * 2 + 1] = p[e1] * denom;
    atomicAdd(&s_cnt[e0], 1); atomicAdd(&s_cnt[e1], 1); atomicAdd(&s_t1[e0], 1);
#pragma unroll
    for (int e = 0; e < N_EXP; e++) atomicAdd(&s_ps[e], p[e]);
    __syncthreads();
    if (tid < N_EXP) {
        atomicAdd(&counts[tid], s_cnt[tid]);
        atomicAdd(&top1cnt[tid], s_t1[tid]);
        atomicAdd(&probs_sum[tid], s_ps[tid]);
    }
}

// ---- scan: offsets, both tile tables, aux loss ----
__global__ void scan_kernel(const int* counts, const int* top1cnt, const float* probs_sum,
                            int* segOff, int* cursors, int* tileE, int* tileB,
                            int* tileE2, int* tileB2, float* aux_out) {
    if (threadIdx.x == 0 && blockIdx.x == 0) {
        int off = 0, nt = 0, nt2 = 0;
        for (int e = 0; e < N_EXP; e++) {
            segOff[e] = off; cursors[e] = off;
            int c = counts[e]; off += c;
            int t = (c + BM - 1) / BM;
            for (int i = 0; i < t; i++) { tileE[nt] = e; tileB[nt] = i * BM; nt++; }
            int t2 = (c + 255) / 256;
            for (int i = 0; i < t2; i++) { tileE2[nt2] = e; tileB2[nt2] = i * 256; nt2++; }
        }
        segOff[N_EXP] = off;
        for (int i = nt; i < MAXT; i++) { tileE[i] = -1; tileB[i] = 0; }
        for (int i = nt2; i < MAXT2; i++) { tileE2[i] = -1; tileB2[i] = 0; }
        float aux = 0.f;
        for (int e = 0; e < N_EXP; e++) aux += (float)top1cnt[e] * probs_sum[e];
        aux_out[0] = (float)N_EXP * aux / ((float)N_TOK * (float)N_TOK);
    }
}

// ---- scatter ----
__global__ __launch_bounds__(64) void scatter_kernel(
    const int* __restrict__ tk_e, const float* __restrict__ tk_w,
    int* cursors, int* rowTok, float* rowGate, int* pairPos) {
    int tok = blockIdx.x * 64 + threadIdx.x;
#pragma unroll
    for (int k = 0; k < 2; k++) {
        int e = tk_e[tok * 2 + k];
        int pos = atomicAdd(&cursors[e], 1);
        rowTok[pos] = tok;
        rowGate[pos] = tk_w[tok * 2 + k];
        pairPos[tok * 2 + k] = pos;
    }
}

// ---- gather x rows -> bf16 Xg ----
__global__ __launch_bounds__(192) void gather_kernel(
    const float* __restrict__ x, const int* __restrict__ rowTok, unsigned short* __restrict__ Xg) {
    int pos = blockIdx.x;
    int t = rowTok[pos];
    int i = threadIdx.x;
    float4 v = ((const float4*)(x + (size_t)t * D_IN))[i];
    unsigned long long pk = (unsigned long long)f2bf(v.x)
                          | ((unsigned long long)f2bf(v.y) << 16)
                          | ((unsigned long long)f2bf(v.z) << 32)
                          | ((unsigned long long)f2bf(v.w) << 48);
    *(unsigned long long*)(Xg + (size_t)pos * D_IN + (size_t)i * 4) = pk;
}

// ---- ffn1g: T = Xg @ Wc^T + bias (grouped, 256x256 tile, BK=64, counted-vmcnt) ----
// Wc[e][n][d]: n<3072 -> W1^T, n>=3072 -> W2^T. 512 thr, 8 waves 2m x 4n, wave tile 128x64.
__global__ __launch_bounds__(512, 2) void ffn1g_kernel(
    const unsigned short* __restrict__ Xg, const unsigned short* __restrict__ Wc,
    const float* __restrict__ b1, const float* __restrict__ b2,
    unsigned short* __restrict__ Tbuf,
    const int* __restrict__ tileE2, const int* __restrict__ tileB2,
    const int* __restrict__ segOff, const int* __restrict__ counts) {
    int bx = blockIdx.x;
    int e = tileE2[bx];
    if (e < 0) return;
    int lb = tileB2[bx];
    int g0 = segOff[e] + lb;
    int vr = counts[e] - lb; if (vr > 256) vr = 256;
    int n0 = blockIdx.y * 256;

    __shared__ __align__(16) unsigned short sA[2][256 * 64]; // 64 KB
    __shared__ __align__(16) unsigned short sB[2][256 * 64]; // 64 KB

    int tid = threadIdx.x, lane = tid & 63, w = tid >> 6;
    int wm = w >> 2, wn = w & 3;      // 2m x 4n
    int lr = lane & 15, lh = lane >> 4;

    f32x4 acc[8][4];
#pragma unroll
    for (int a = 0; a < 8; a++)
#pragma unroll
        for (int b = 0; b < 4; b++) acc[a][b] = (f32x4)0.f;

    const unsigned short* We = Wc + (size_t)e * NC * D_IN;

    // row-major LDS rows of 64 bf16 (128B), 16B-chunk XOR swizzle c ^= row&7.
    // part q = rows q*64 .. q*64+63 (8KB = 512 thr x 16B)
    auto stageA = [&](int buf, int kt, int q) {
        int o = q * 8192 + tid * 16;
        int row = o >> 7;
        int c = ((o >> 4) & 7) ^ (row & 7);
        int gr = g0 + row; if (gr > NP - 1) gr = NP - 1;
        gload_lds16(Xg + (size_t)gr * D_IN + kt * 64 + c * 8, (char*)&sA[buf][0] + o);
    };
    auto stageB = [&](int buf, int kt, int q) {
        int o = q * 8192 + tid * 16;
        int row = o >> 7;
        int c = ((o >> 4) & 7) ^ (row & 7);
        gload_lds16(We + (size_t)(n0 + row) * D_IN + kt * 64 + c * 8, (char*)&sB[buf][0] + o);
    };

    const int NKT = D_IN / BK; // 12
    // prologue: tile 0, issue order B0,B1,B2,B3, A0,A2,A1,A3
    stageB(0, 0, 0); stageB(0, 0, 1); stageB(0, 0, 2); stageB(0, 0, 3);
    stageA(0, 0, 0); stageA(0, 0, 2); stageA(0, 0, 1); stageA(0, 0, 3);
    __builtin_amdgcn_sched_barrier(0);

#pragma unroll 1
    for (int kt = 0; kt < NKT; ++kt) {
        int cur = kt & 1, nxt = cur ^ 1;
        bool more = (kt + 1 < NKT);
        // entry: outstanding = this tile's 8 loads. Oldest 6 = B0-3, A0, A2.
        asm volatile("s_waitcnt vmcnt(2)" ::: "memory");
        __builtin_amdgcn_s_barrier();   // block-wide: everyone's B + phase-A A-parts landed
        __builtin_amdgcn_sched_barrier(0);

        // B fragments for both k-slices (kept across both phases)
        s16x8 bv[2][4];
#pragma unroll
        for (int ks = 0; ks < 2; ++ks)
#pragma unroll
            for (int nf = 0; nf < 4; ++nf) {
                int n = wn * 64 + nf * 16 + lr;
                int sb = ks * 4 + lh;
                bv[ks][nf] = *(const s16x8*)&sB[cur][n * 64 + ((sb ^ (n & 7)) << 3)];
            }
        // phase A: m-frags 0..3 (rows wm*128 + 0..63 = A part 2*wm)
        s16x8 av[2][4];
#pragma unroll
        for (int ks = 0; ks < 2; ++ks)
#pragma unroll
            for (int mf = 0; mf < 4; ++mf) {
                int r = wm * 128 + mf * 16 + lr;
                av[ks][mf] = *(const s16x8*)&sA[cur][r * 64 + (((ks * 4 + lh) ^ (r & 7)) << 3)];
            }
        __builtin_amdgcn_sched_barrier(0);
        if (more) { stageB(nxt, kt + 1, 0); stageB(nxt, kt + 1, 1); stageB(nxt, kt + 1, 2); stageB(nxt, kt + 1, 3); }
        __builtin_amdgcn_sched_barrier(0);
        __builtin_amdgcn_s_setprio(1);
#pragma unroll
        for (int ks = 0; ks < 2; ++ks)
#pragma unroll
            for (int nf = 0; nf < 4; ++nf)
#pragma unroll
                for (int mf = 0; mf < 4; ++mf)
                    acc[mf][nf] = __builtin_amdgcn_mfma_f32_16x16x32_bf16(av[ks][mf], bv[ks][nf], acc[mf][nf], 0, 0, 0);
        __builtin_amdgcn_s_setprio(0);
        __builtin_amdgcn_sched_barrier(0);

        // mid: outstanding = {A1,A3 of this tile} + {B0-3 of next} = 6 -> wait oldest 2
        if (more) { asm volatile("s_waitcnt vmcnt(4)" ::: "memory"); }
        else      { asm volatile("s_waitcnt vmcnt(0)" ::: "memory"); }
        __builtin_amdgcn_s_barrier();   // block-wide: phase-B A-parts landed
        __builtin_amdgcn_sched_barrier(0);

        // phase B: m-frags 4..7 (rows wm*128 + 64..127 = A part 2*wm+1)
#pragma unroll
        for (int ks = 0; ks < 2; ++ks)
#pragma unroll
            for (int mf = 0; mf < 4; ++mf) {
                int r = wm * 128 + 64 + mf * 16 + lr;
                av[ks][mf] = *(const s16x8*)&sA[cur][r * 64 + (((ks * 4 + lh) ^ (r & 7)) << 3)];
            }
        __builtin_amdgcn_sched_barrier(0);
        if (more) { stageA(nxt, kt + 1, 0); stageA(nxt, kt + 1, 2); stageA(nxt, kt + 1, 1); stageA(nxt, kt + 1, 3); }
        __builtin_amdgcn_sched_barrier(0);
        __builtin_amdgcn_s_setprio(1);
#pragma unroll
        for (int ks = 0; ks < 2; ++ks)
#pragma unroll
            for (int nf = 0; nf < 4; ++nf)
#pragma unroll
                for (int mf = 0; mf < 4; ++mf)
                    acc[4 + mf][nf] = __builtin_amdgcn_mfma_f32_16x16x32_bf16(av[ks][mf], bv[ks][nf], acc[4 + mf][nf], 0, 0, 0);
        __builtin_amdgcn_s_setprio(0);
        __builtin_amdgcn_sched_barrier(0);
    }

    // epilogue: bias add, bf16 store. col n = n0 + wn*64 + nf*16 + lr (block uniform half)
    const float* bias = (n0 < H_DIM) ? (b1 + e * H_DIM + n0) : (b2 + e * H_DIM + (n0 - H_DIM));
#pragma unroll
    for (int mf = 0; mf < 8; ++mf) {
        int rbase = wm * 128 + mf * 16 + lh * 4;
#pragma unroll
        for (int nf = 0; nf < 4; ++nf) {
            int nl = wn * 64 + nf * 16 + lr;
            float bb = bias[nl];
#pragma unroll
            for (int j = 0; j < 4; ++j) {
                int r = rbase + j;
                if (r < vr)
                    Tbuf[(size_t)(g0 + r) * NC + n0 + nl] = f2bf(acc[mf][nf][j] + bb);
            }
        }
    }
}

// ---- silu-mul: Hb[m][j] = silu(T[m][j]) * T[m][j+3072] ----
__global__ __launch_bounds__(256) void silumul_kernel(
    const unsigned short* __restrict__ T, unsigned short* __restrict__ Hb) {
    int idx = blockIdx.x * 256 + threadIdx.x; // NP*384 total
    int m = idx / 384;
    int j = (idx - m * 384) * 8;
    s16x8 a = *(const s16x8*)&T[(size_t)m * NC + j];
    s16x8 b = *(const s16x8*)&T[(size_t)m * NC + H_DIM + j];
    s16x8 o;
#pragma unroll
    for (int i = 0; i < 8; i++) {
        float x1 = bf2f((unsigned short)a[i]);
        float x2 = bf2f((unsigned short)b[i]);
        float h = x1 / (1.f + __expf(-x1)) * x2;
        o[i] = (short)f2bf(h);
    }
    *(s16x8*)&Hb[(size_t)m * H_DIM + j] = o;
}

// ---- ffn2: Y = gate * (H@W3 + b3), f32 out (R3 structure kept) ----
__global__ __launch_bounds__(512) void ffn2_kernel(
    const unsigned short* __restrict__ Hbuf, const unsigned short* __restrict__ W3T,
    const float* __restrict__ b3, const float* __restrict__ rowGate,
    float* __restrict__ Ybuf,
    const int* __restrict__ tileE, const int* __restrict__ tileB,
    const int* __restrict__ segOff, const int* __restrict__ counts) {
    int bx = blockIdx.x;
    int e = tileE[bx];
    if (e < 0) return;
    int lb = tileB[bx];
    int g0 = segOff[e] + lb;
    int vr = counts[e] - lb; if (vr > BM) vr = BM;
    int n0 = blockIdx.y * BN2;

    __shared__ __align__(16) unsigned short sA[2][BM * BK];
    __shared__ __align__(16) unsigned short sB[2][BN2 * BK];

    int tid = threadIdx.x, lane = tid & 63, w = tid >> 6;
    int wm = w >> 2, wn = w & 3;
    int lr = lane & 15, lh = lane >> 4;

    f32x4 acc[4][2];
#pragma unroll
    for (int a = 0; a < 4; a++)
#pragma unroll
        for (int b = 0; b < 2; b++) acc[a][b] = (f32x4)0.f;

    const unsigned short* W3e = W3T + (size_t)e * D_IN * H_DIM;

    auto stage = [&](int buf, int kt) {
        int kb = kt * BK;
#pragma unroll
        for (int ca = 0; ca < 2; ca++) {
            int o = ca * 8192 + tid * 16;
            int row = o >> 7;
            int c = ((o >> 4) & 7) ^ (row & 7);
            int gr = g0 + row; if (gr > NP - 1) gr = NP - 1;
            gload_lds16(Hbuf + (size_t)gr * H_DIM + kb + c * 8, (char*)&sA[buf][0] + o);
        }
#pragma unroll
        for (int cb = 0; cb < 2; cb++) {
            int o = cb * 8192 + tid * 16;
            int row = o >> 7;
            int c = ((o >> 4) & 7) ^ (row & 7);
            gload_lds16(W3e + (size_t)(n0 + row) * H_DIM + kb + c * 8, (char*)&sB[buf][0] + o);
        }
    };

    const int NKT = H_DIM / BK; // 48
    stage(0, 0);
    stage(1, 1);
    __builtin_amdgcn_sched_barrier(0);
#pragma unroll 1
    for (int kt = 0; kt < NKT; ++kt) {
        if (kt < NKT - 1) { asm volatile("s_waitcnt vmcnt(4)" ::: "memory"); }
        else              { asm volatile("s_waitcnt vmcnt(0)" ::: "memory"); }
        __builtin_amdgcn_s_barrier();
        __builtin_amdgcn_sched_barrier(0);
        int cur = kt & 1;
#pragma unroll
        for (int ks = 0; ks < 2; ++ks) {
            int sb = ks * 4 + lh;
            s16x8 av[4];
#pragma unroll
            for (int mf = 0; mf < 4; ++mf) {
                int r = wm * 64 + mf * 16 + lr;
                av[mf] = *(const s16x8*)&sA[cur][r * 64 + ((sb ^ (r & 7)) << 3)];
            }
#pragma unroll
            for (int nf = 0; nf < 2; ++nf) {
                int n = wn * 32 + nf * 16 + lr;
                s16x8 bv = *(const s16x8*)&sB[cur][n * 64 + ((sb ^ (n & 7)) << 3)];
#pragma unroll
                for (int mf = 0; mf < 4; ++mf)
                    acc[mf][nf] = __builtin_amdgcn_mfma_f32_16x16x32_bf16(av[mf], bv, acc[mf][nf], 0, 0, 0);
            }
        }
        __builtin_amdgcn_sched_barrier(0);
        __builtin_amdgcn_s_barrier();
        if (kt + 2 < NKT) { stage(cur, kt + 2); __builtin_amdgcn_sched_barrier(0); }
    }
#pragma unroll
    for (int mf = 0; mf < 4; ++mf) {
        int rbase = wm * 64 + mf * 16 + lh * 4;
#pragma unroll
        for (int nf = 0; nf < 2; ++nf) {
            int n = n0 + wn * 32 + nf * 16 + lr;
            float bb = b3[e * D_IN + n];
#pragma unroll
            for (int j = 0; j < 4; ++j) {
                int r = rbase + j;
                if (r < vr) {
                    float g = rowGate[g0 + r];
                    Ybuf[(size_t)(g0 + r) * D_IN + n] = g * (acc[mf][nf][j] + bb);
                }
            }
        }
    }
}

// ---- combine ----
__global__ __launch_bounds__(192) void combine_kernel(
    const float* __restrict__ Ybuf, const int* __restrict__ pairPos, float* __restrict__ out) {
    int t = blockIdx.x, i = threadIdx.x;
    int p0 = pairPos[t * 2], p1 = pairPos[t * 2 + 1];
    float4 a = ((const float4*)(Ybuf + (size_t)p0 * D_IN))[i];
    float4 b = ((const float4*)(Ybuf + (size_t)p1 * D_IN))[i];
    float4 r; r.x = a.x + b.x; r.y = a.y + b.y; r.z = a.z + b.z; r.w = a.w + b.w;
    ((float4*)(out + (size_t)t * D_IN))[i] = r;
}

extern "C" void kernel_launch(void* const* d_in, const int* in_sizes, int n_in,
                              void* d_out, int out_size, void* d_ws, size_t ws_size,
                              hipStream_t stream) {
    const float* x  = (const float*)d_in[0];
    const float* rw = (const float*)d_in[1];
    const float* rb = (const float*)d_in[2];
    const float* w1 = (const float*)d_in[3];
    const float* b1 = (const float*)d_in[4];
    const float* w2 = (const float*)d_in[5];
    const float* b2 = (const float*)d_in[6];
    const float* w3 = (const float*)d_in[7];
    const float* b3 = (const float*)d_in[8];
    float* out = (float*)d_out;

    char* ws = (char*)d_ws;
    const size_t sWc  = (size_t)N_EXP * NC * D_IN * 2;       // 75.5 MB
    const size_t sW3  = (size_t)N_EXP * D_IN * H_DIM * 2;    // 37.7 MB
    const size_t sXg  = (size_t)NP * D_IN * 2;               // 12.6 MB
    const size_t sT   = (size_t)NP * NC * 2;                 // 100.7 MB
    const size_t sHb  = (size_t)NP * H_DIM * 2;              // 50.3 MB
    unsigned short* Wc  = (unsigned short*)(ws);
    unsigned short* W3T = (unsigned short*)(ws + sWc);
    unsigned short* Xg  = (unsigned short*)(ws + sWc + sW3);
    unsigned short* Tb  = (unsigned short*)(ws + sWc + sW3 + sXg);
    unsigned short* Hb  = (unsigned short*)(ws + sWc + sW3 + sXg + sT);
    float* Yb = (float*)Tb;   // alias: Tb dead after silumul, Yb written by ffn2
    char* meta = (char*)(ws + sWc + sW3 + sXg + sT + sHb);
    int*   counts  = (int*)(meta + 0);
    int*   top1    = (int*)(meta + 32);
    float* psum    = (float*)(meta + 64);
    int*   cursors = (int*)(meta + 96);
    int*   segOff  = (int*)(meta + 128);
    int*   tileE   = (int*)(meta + 192);
    int*   tileB   = (int*)(meta + 512);
    int*   tileE2  = (int*)(meta + 1024);
    int*   tileB2  = (int*)(meta + 1280);
    int*   tk_e    = (int*)(meta + 2048);
    float* tk_w    = (float*)(meta + 2048 + 32768);
    int*   rowTok  = (int*)(meta + 2048 + 65536);
    float* rowGate = (float*)(meta + 2048 + 98304);
    int*   pairPos = (int*)(meta + 2048 + 131072);
    size_t need = (size_t)(meta - ws) + 2048 + 131072 + 32768;
    if (ws_size < need) return;

    hipMemsetAsync(meta, 0, 96, stream);
    dim3 tb(32, 8);
    transpose_cvt_kernel<<<dim3(H_DIM / 32, D_IN / 32, N_EXP), tb, 0, stream>>>(
        w1, Wc, D_IN, H_DIM, (size_t)NC * D_IN, 0);
    transpose_cvt_kernel<<<dim3(H_DIM / 32, D_IN / 32, N_EXP), tb, 0, stream>>>(
        w2, Wc, D_IN, H_DIM, (size_t)NC * D_IN, H_DIM);
    transpose_cvt_kernel<<<dim3(D_IN / 32, H_DIM / 32, N_EXP), tb, 0, stream>>>(
        w3, W3T, H_DIM, D_IN, (size_t)D_IN * H_DIM, 0);
    router_kernel<<<N_TOK / 64, 64, 0, stream>>>(x, rw, rb, counts, top1, psum, tk_e, tk_w);
    scan_kernel<<<1, 64, 0, stream>>>(counts, top1, psum, segOff, cursors, tileE, tileB,
                                      tileE2, tileB2, out + (size_t)N_TOK * D_IN);
    scatter_kernel<<<N_TOK / 64, 64, 0, stream>>>(tk_e, tk_w, cursors, rowTok, rowGate, pairPos);
    gather_kernel<<<NP, 192, 0, stream>>>(x, rowTok, Xg);
    ffn1g_kernel<<<dim3(MAXT2, NC / 256), 512, 0, stream>>>(Xg, Wc, b1, b2, Tb,
                                                            tileE2, tileB2, segOff, counts);
    silumul_kernel<<<NP * 384 / 256, 256, 0, stream>>>(Tb, Hb);
    ffn2_kernel<<<dim3(MAXT, D_IN / BN2), 512, 0, stream>>>(Hb, W3T, b3, rowGate, Yb,
                                                            tileE, tileB, segOff, counts);
    combine_kernel<<<N_TOK, 192, 0, stream>>>(Yb, pairPos, out);
}

// Round 5
// 348.399 us; speedup vs baseline: 1.2389x; 1.2389x over previous
//
#include <hip/hip_runtime.h>
#include <hip/hip_bf16.h>
#include <math.h>

#define N_TOK 4096
#define D_IN  768
#define N_EXP 8
#define H_DIM 3072
#define NP    8192      // N_TOK * TOPK
#define BM    128
#define BK    64
#define BN1   64
#define BN2   128
#define MAXT  72        // NP/BM + N_EXP
#define GRID1 (MAXT * (H_DIM / BN1))   // 3456, divisible by 8
#define GRID2 (MAXT * (D_IN / BN2))    // 432, divisible by 8

typedef float f32x4 __attribute__((ext_vector_type(4)));
typedef short s16x8 __attribute__((ext_vector_type(8)));

__device__ __forceinline__ unsigned short f2bf(float f) {
    unsigned int u = __builtin_bit_cast(unsigned int, f);
    u += 0x7fffu + ((u >> 16) & 1u);
    return (unsigned short)(u >> 16);
}

__device__ __forceinline__ void gload_lds16(const void* g, void* l) {
    __builtin_amdgcn_global_load_lds(
        (const __attribute__((address_space(1))) unsigned int*)g,
        (__attribute__((address_space(3))) unsigned int*)l, 16, 0, 0);
}

// bijective XCD-chunk swizzle: consecutive logical ids stay on one XCD.
// nblk must be divisible by 8.
__device__ __forceinline__ int xcd_swz(int bid, int nblk) {
    int chunk = nblk >> 3;
    return (bid & 7) * chunk + (bid >> 3);
}

// ---- transpose + f32->bf16: src[e][R][C] -> dst[e*eStride + (rowOff+c)*R + r] ----
// 32x32 tiles; coalesced f32 loads, 8B packed bf16 stores.
__global__ __launch_bounds__(256) void transpose_cvt_kernel(
    const float* __restrict__ src, unsigned short* __restrict__ dst, int R, int C,
    size_t eStride, int rowOff) {
    __shared__ float t[32][33];
    int e = blockIdx.z;
    int c0 = blockIdx.x * 32, r0 = blockIdx.y * 32;
    int tid = threadIdx.x;
    const float* s = src + (size_t)e * R * C;
    unsigned short* d = dst + (size_t)e * eStride;
    int lc = tid & 31, r4 = tid >> 5;        // phase 1: c fastest
#pragma unroll
    for (int i = 0; i < 4; i++)
        t[r4 * 4 + i][lc] = s[(size_t)(r0 + r4 * 4 + i) * C + c0 + lc];
    __syncthreads();
    int rq = tid & 7, c = tid >> 3;          // phase 2: r-quad fastest
    unsigned long long pk =
          (unsigned long long)f2bf(t[rq * 4 + 0][c])
        | ((unsigned long long)f2bf(t[rq * 4 + 1][c]) << 16)
        | ((unsigned long long)f2bf(t[rq * 4 + 2][c]) << 32)
        | ((unsigned long long)f2bf(t[rq * 4 + 3][c]) << 48);
    *(unsigned long long*)&d[(size_t)(rowOff + c0 + c) * R + r0 + rq * 4] = pk;
}

// ---- router ----
__global__ __launch_bounds__(64) void router_kernel(
    const float* __restrict__ x, const float* __restrict__ rw, const float* __restrict__ rb,
    int* counts, int* top1cnt, float* probs_sum, int* tk_e, float* tk_w) {
    __shared__ __align__(16) float s_rw[D_IN * N_EXP];
    __shared__ float s_ps[N_EXP];
    __shared__ int s_cnt[N_EXP], s_t1[N_EXP];
    int tid = threadIdx.x;
    for (int i = tid; i < D_IN * N_EXP / 4; i += 64)
        ((float4*)s_rw)[i] = ((const float4*)rw)[i];
    if (tid < N_EXP) { s_ps[tid] = 0.f; s_cnt[tid] = 0; s_t1[tid] = 0; }
    __syncthreads();

    int tok = blockIdx.x * 64 + tid;
    float acc[N_EXP];
#pragma unroll
    for (int e = 0; e < N_EXP; e++) acc[e] = rb[e];
    const float* xr = x + (size_t)tok * D_IN;
    for (int d = 0; d < D_IN; d++) {
        float xv = xr[d];
#pragma unroll
        for (int e = 0; e < N_EXP; e++) acc[e] += xv * s_rw[d * N_EXP + e];
    }
    float m = acc[0];
#pragma unroll
    for (int e = 1; e < N_EXP; e++) m = fmaxf(m, acc[e]);
    float p[N_EXP], s = 0.f;
#pragma unroll
    for (int e = 0; e < N_EXP; e++) { p[e] = __expf(acc[e] - m); s += p[e]; }
    float inv = 1.f / s;
#pragma unroll
    for (int e = 0; e < N_EXP; e++) p[e] *= inv;
    int e0 = 0;
#pragma unroll
    for (int e = 1; e < N_EXP; e++) if (p[e] > p[e0]) e0 = e;
    int e1 = (e0 == 0) ? 1 : 0;
#pragma unroll
    for (int e = 0; e < N_EXP; e++) if (e != e0 && p[e] > p[e1]) e1 = e;
    float denom = 1.f / (p[e0] + p[e1]);
    tk_e[tok * 2] = e0; tk_e[tok * 2 + 1] = e1;
    tk_w[tok * 2] = p[e0] * denom; tk_w[tok * 2 + 1] = p[e1] * denom;
    atomicAdd(&s_cnt[e0], 1); atomicAdd(&s_cnt[e1], 1); atomicAdd(&s_t1[e0], 1);
#pragma unroll
    for (int e = 0; e < N_EXP; e++) atomicAdd(&s_ps[e], p[e]);
    __syncthreads();
    if (tid < N_EXP) {
        atomicAdd(&counts[tid], s_cnt[tid]);
        atomicAdd(&top1cnt[tid], s_t1[tid]);
        atomicAdd(&probs_sum[tid], s_ps[tid]);
    }
}

// ---- scan ----
__global__ void scan_kernel(const int* counts, const int* top1cnt, const float* probs_sum,
                            int* segOff, int* cursors, int* tileE, int* tileB,
                            float* aux_out) {
    if (threadIdx.x == 0 && blockIdx.x == 0) {
        int off = 0, nt = 0;
        for (int e = 0; e < N_EXP; e++) {
            segOff[e] = off; cursors[e] = off;
            int c = counts[e]; off += c;
            int t = (c + BM - 1) / BM;
            for (int i = 0; i < t; i++) { tileE[nt] = e; tileB[nt] = i * BM; nt++; }
        }
        segOff[N_EXP] = off;
        for (int i = nt; i < MAXT; i++) { tileE[i] = -1; tileB[i] = 0; }
        float aux = 0.f;
        for (int e = 0; e < N_EXP; e++) aux += (float)top1cnt[e] * probs_sum[e];
        aux_out[0] = (float)N_EXP * aux / ((float)N_TOK * (float)N_TOK);
    }
}

// ---- scatter ----
__global__ __launch_bounds__(64) void scatter_kernel(
    const int* __restrict__ tk_e, const float* __restrict__ tk_w,
    int* cursors, int* rowTok, float* rowGate, int* pairPos) {
    int tok = blockIdx.x * 64 + threadIdx.x;
#pragma unroll
    for (int k = 0; k < 2; k++) {
        int e = tk_e[tok * 2 + k];
        int pos = atomicAdd(&cursors[e], 1);
        rowTok[pos] = tok;
        rowGate[pos] = tk_w[tok * 2 + k];
        pairPos[tok * 2 + k] = pos;
    }
}

// ---- gather ----
__global__ __launch_bounds__(192) void gather_kernel(
    const float* __restrict__ x, const int* __restrict__ rowTok, unsigned short* __restrict__ Xg) {
    int pos = blockIdx.x;
    int t = rowTok[pos];
    int i = threadIdx.x;
    float4 v = ((const float4*)(x + (size_t)t * D_IN))[i];
    unsigned long long pk = (unsigned long long)f2bf(v.x)
                          | ((unsigned long long)f2bf(v.y) << 16)
                          | ((unsigned long long)f2bf(v.z) << 32)
                          | ((unsigned long long)f2bf(v.w) << 48);
    *(unsigned long long*)(Xg + (size_t)pos * D_IN + (size_t)i * 4) = pk;
}

// ---- ffn1: H = silu(X@W1+b1) * (X@W2+b2), bf16 out ----
// R1 structure (measured best): BM=128 BN1=64 BK=64, 256 thr, single-buffer 2-phase.
// + XCD-chunked swizzle, by-fastest in chunk (A-tile L2 reuse).
__global__ __launch_bounds__(256) void ffn1_kernel(
    const unsigned short* __restrict__ Xg, const unsigned short* __restrict__ W1T,
    const unsigned short* __restrict__ W2T, const float* __restrict__ b1,
    const float* __restrict__ b2, unsigned short* __restrict__ Hbuf,
    const int* __restrict__ tileE, const int* __restrict__ tileB,
    const int* __restrict__ segOff, const int* __restrict__ counts) {
    int u = xcd_swz(blockIdx.x, GRID1);
    int bx = u / (H_DIM / BN1);
    int by = u - bx * (H_DIM / BN1);
    int e = tileE[bx];
    if (e < 0) return;
    int lb = tileB[bx];
    int g0 = segOff[e] + lb;
    int vr = counts[e] - lb; if (vr > BM) vr = BM;
    int n0 = by * BN1;

    __shared__ __align__(16) unsigned short sA[BM * BK];
    __shared__ __align__(16) unsigned short sB1[BN1 * BK];
    __shared__ __align__(16) unsigned short sB2[BN1 * BK];

    int tid = threadIdx.x, lane = tid & 63, w = tid >> 6;
    int wm = w >> 1, wn = w & 1;
    int lr = lane & 15, lh = lane >> 4;

    f32x4 acc1[4][2], acc2[4][2];
#pragma unroll
    for (int a = 0; a < 4; a++)
#pragma unroll
        for (int b = 0; b < 2; b++) { acc1[a][b] = (f32x4)0.f; acc2[a][b] = (f32x4)0.f; }

    const unsigned short* W1e = W1T + (size_t)e * H_DIM * D_IN;
    const unsigned short* W2e = W2T + (size_t)e * H_DIM * D_IN;

    for (int kt = 0; kt < D_IN / BK; ++kt) {
        int kb = kt * BK;
#pragma unroll
        for (int ra = 0; ra < 4; ra++) {
            int o = ra * 4096 + tid * 16;
            int row = o >> 7;
            int c = ((o >> 4) & 7) ^ (row & 7);
            int gr = g0 + row; if (gr > NP - 1) gr = NP - 1;
            gload_lds16(Xg + (size_t)gr * D_IN + kb + c * 8, (char*)sA + o);
        }
#pragma unroll
        for (int rb2 = 0; rb2 < 2; rb2++) {
            int o = rb2 * 4096 + tid * 16;
            int row = o >> 7;
            int c = ((o >> 4) & 7) ^ (row & 7);
            size_t src = (size_t)(n0 + row) * D_IN + kb + c * 8;
            gload_lds16(W1e + src, (char*)sB1 + o);
            gload_lds16(W2e + src, (char*)sB2 + o);
        }
        asm volatile("s_waitcnt vmcnt(0)" ::: "memory");
        __syncthreads();
#pragma unroll
        for (int ks = 0; ks < 2; ++ks) {
            int sb = ks * 4 + lh;
            s16x8 av[4];
#pragma unroll
            for (int mf = 0; mf < 4; ++mf) {
                int r = wm * 64 + mf * 16 + lr;
                av[mf] = *(const s16x8*)&sA[r * 64 + ((sb ^ (r & 7)) << 3)];
            }
#pragma unroll
            for (int nf = 0; nf < 2; ++nf) {
                int n = wn * 32 + nf * 16 + lr;
                int off = n * 64 + ((sb ^ (n & 7)) << 3);
                s16x8 bv1 = *(const s16x8*)&sB1[off];
                s16x8 bv2 = *(const s16x8*)&sB2[off];
#pragma unroll
                for (int mf = 0; mf < 4; ++mf) {
                    acc1[mf][nf] = __builtin_amdgcn_mfma_f32_16x16x32_bf16(av[mf], bv1, acc1[mf][nf], 0, 0, 0);
                    acc2[mf][nf] = __builtin_amdgcn_mfma_f32_16x16x32_bf16(av[mf], bv2, acc2[mf][nf], 0, 0, 0);
                }
            }
        }
        __syncthreads();
    }
#pragma unroll
    for (int mf = 0; mf < 4; ++mf) {
        int rbase = wm * 64 + mf * 16 + lh * 4;
#pragma unroll
        for (int nf = 0; nf < 2; ++nf) {
            int n = n0 + wn * 32 + nf * 16 + lr;
            float bb1 = b1[e * H_DIM + n], bb2 = b2[e * H_DIM + n];
#pragma unroll
            for (int j = 0; j < 4; ++j) {
                int r = rbase + j;
                if (r < vr) {
                    float x1 = acc1[mf][nf][j] + bb1;
                    float x2 = acc2[mf][nf][j] + bb2;
                    float h = x1 / (1.f + __expf(-x1)) * x2;
                    Hbuf[(size_t)(g0 + r) * H_DIM + n] = f2bf(h);
                }
            }
        }
    }
}

// ---- ffn2: Y = gate * (H@W3 + b3), f32 out ----
// R3 structure (measured good): BM=128 BN2=128 BK=64, 512 thr, counted-vmcnt dbuf.
__global__ __launch_bounds__(512) void ffn2_kernel(
    const unsigned short* __restrict__ Hbuf, const unsigned short* __restrict__ W3T,
    const float* __restrict__ b3, const float* __restrict__ rowGate,
    float* __restrict__ Ybuf,
    const int* __restrict__ tileE, const int* __restrict__ tileB,
    const int* __restrict__ segOff, const int* __restrict__ counts) {
    int u = xcd_swz(blockIdx.x, GRID2);
    int bx = u / (D_IN / BN2);
    int by = u - bx * (D_IN / BN2);
    int e = tileE[bx];
    if (e < 0) return;
    int lb = tileB[bx];
    int g0 = segOff[e] + lb;
    int vr = counts[e] - lb; if (vr > BM) vr = BM;
    int n0 = by * BN2;

    __shared__ __align__(16) unsigned short sA[2][BM * BK];
    __shared__ __align__(16) unsigned short sB[2][BN2 * BK];

    int tid = threadIdx.x, lane = tid & 63, w = tid >> 6;
    int wm = w >> 2, wn = w & 3;      // 2 x 4 waves, wave tile 64 x 32
    int lr = lane & 15, lh = lane >> 4;

    f32x4 acc[4][2];
#pragma unroll
    for (int a = 0; a < 4; a++)
#pragma unroll
        for (int b = 0; b < 2; b++) acc[a][b] = (f32x4)0.f;

    const unsigned short* W3e = W3T + (size_t)e * D_IN * H_DIM;

    auto stage = [&](int buf, int kt) {
        int kb = kt * BK;
#pragma unroll
        for (int ca = 0; ca < 2; ca++) {
            int o = ca * 8192 + tid * 16;
            int row = o >> 7;
            int c = ((o >> 4) & 7) ^ (row & 7);
            int gr = g0 + row; if (gr > NP - 1) gr = NP - 1;
            gload_lds16(Hbuf + (size_t)gr * H_DIM + kb + c * 8, (char*)&sA[buf][0] + o);
        }
#pragma unroll
        for (int cb = 0; cb < 2; cb++) {
            int o = cb * 8192 + tid * 16;
            int row = o >> 7;
            int c = ((o >> 4) & 7) ^ (row & 7);
            gload_lds16(W3e + (size_t)(n0 + row) * H_DIM + kb + c * 8, (char*)&sB[buf][0] + o);
        }
    };

    const int NKT = H_DIM / BK; // 48
    stage(0, 0);
    stage(1, 1);
    __builtin_amdgcn_sched_barrier(0);
#pragma unroll 1
    for (int kt = 0; kt < NKT; ++kt) {
        if (kt < NKT - 1) { asm volatile("s_waitcnt vmcnt(4)" ::: "memory"); }
        else              { asm volatile("s_waitcnt vmcnt(0)" ::: "memory"); }
        __builtin_amdgcn_s_barrier();
        __builtin_amdgcn_sched_barrier(0);
        int cur = kt & 1;
#pragma unroll
        for (int ks = 0; ks < 2; ++ks) {
            int sb = ks * 4 + lh;
            s16x8 av[4];
#pragma unroll
            for (int mf = 0; mf < 4; ++mf) {
                int r = wm * 64 + mf * 16 + lr;
                av[mf] = *(const s16x8*)&sA[cur][r * 64 + ((sb ^ (r & 7)) << 3)];
            }
#pragma unroll
            for (int nf = 0; nf < 2; ++nf) {
                int n = wn * 32 + nf * 16 + lr;
                s16x8 bv = *(const s16x8*)&sB[cur][n * 64 + ((sb ^ (n & 7)) << 3)];
#pragma unroll
                for (int mf = 0; mf < 4; ++mf)
                    acc[mf][nf] = __builtin_amdgcn_mfma_f32_16x16x32_bf16(av[mf], bv, acc[mf][nf], 0, 0, 0);
            }
        }
        __builtin_amdgcn_sched_barrier(0);
        __builtin_amdgcn_s_barrier();
        if (kt + 2 < NKT) { stage(cur, kt + 2); __builtin_amdgcn_sched_barrier(0); }
    }
#pragma unroll
    for (int mf = 0; mf < 4; ++mf) {
        int rbase = wm * 64 + mf * 16 + lh * 4;
#pragma unroll
        for (int nf = 0; nf < 2; ++nf) {
            int n = n0 + wn * 32 + nf * 16 + lr;
            float bb = b3[e * D_IN + n];
#pragma unroll
            for (int j = 0; j < 4; ++j) {
                int r = rbase + j;
                if (r < vr) {
                    float g = rowGate[g0 + r];
                    Ybuf[(size_t)(g0 + r) * D_IN + n] = g * (acc[mf][nf][j] + bb);
                }
            }
        }
    }
}

// ---- combine ----
__global__ __launch_bounds__(192) void combine_kernel(
    const float* __restrict__ Ybuf, const int* __restrict__ pairPos, float* __restrict__ out) {
    int t = blockIdx.x, i = threadIdx.x;
    int p0 = pairPos[t * 2], p1 = pairPos[t * 2 + 1];
    float4 a = ((const float4*)(Ybuf + (size_t)p0 * D_IN))[i];
    float4 b = ((const float4*)(Ybuf + (size_t)p1 * D_IN))[i];
    float4 r; r.x = a.x + b.x; r.y = a.y + b.y; r.z = a.z + b.z; r.w = a.w + b.w;
    ((float4*)(out + (size_t)t * D_IN))[i] = r;
}

extern "C" void kernel_launch(void* const* d_in, const int* in_sizes, int n_in,
                              void* d_out, int out_size, void* d_ws, size_t ws_size,
                              hipStream_t stream) {
    const float* x  = (const float*)d_in[0];
    const float* rw = (const float*)d_in[1];
    const float* rb = (const float*)d_in[2];
    const float* w1 = (const float*)d_in[3];
    const float* b1 = (const float*)d_in[4];
    const float* w2 = (const float*)d_in[5];
    const float* b2 = (const float*)d_in[6];
    const float* w3 = (const float*)d_in[7];
    const float* b3 = (const float*)d_in[8];
    float* out = (float*)d_out;

    char* ws = (char*)d_ws;
    const size_t sW = (size_t)N_EXP * H_DIM * D_IN * 2;
    unsigned short* W1T = (unsigned short*)(ws);
    unsigned short* W2T = (unsigned short*)(ws + sW);
    unsigned short* W3T = (unsigned short*)(ws + 2 * sW);
    unsigned short* Xg  = (unsigned short*)(ws + 3 * sW);
    unsigned short* Hb  = (unsigned short*)(ws + 3 * sW + (size_t)NP * D_IN * 2);
    float* Yb = (float*)(ws + 3 * sW + (size_t)NP * D_IN * 2 + (size_t)NP * H_DIM * 2);
    char* meta = (char*)(Yb + (size_t)NP * D_IN);
    int*   counts  = (int*)(meta + 0);
    int*   top1    = (int*)(meta + 32);
    float* psum    = (float*)(meta + 64);
    int*   cursors = (int*)(meta + 96);
    int*   segOff  = (int*)(meta + 128);
    int*   tileE   = (int*)(meta + 192);
    int*   tileB   = (int*)(meta + 512);
    int*   tk_e    = (int*)(meta + 1024);
    float* tk_w    = (float*)(meta + 1024 + 32768);
    int*   rowTok  = (int*)(meta + 1024 + 65536);
    float* rowGate = (float*)(meta + 1024 + 98304);
    int*   pairPos = (int*)(meta + 1024 + 131072);
    size_t need = (size_t)(meta - ws) + 1024 + 131072 + 32768;
    if (ws_size < need) return;

    hipMemsetAsync(meta, 0, 96, stream);
    transpose_cvt_kernel<<<dim3(H_DIM / 32, D_IN / 32, N_EXP), 256, 0, stream>>>(
        w1, W1T, D_IN, H_DIM, (size_t)H_DIM * D_IN, 0);
    transpose_cvt_kernel<<<dim3(H_DIM / 32, D_IN / 32, N_EXP), 256, 0, stream>>>(
        w2, W2T, D_IN, H_DIM, (size_t)H_DIM * D_IN, 0);
    transpose_cvt_kernel<<<dim3(D_IN / 32, H_DIM / 32, N_EXP), 256, 0, stream>>>(
        w3, W3T, H_DIM, D_IN, (size_t)D_IN * H_DIM, 0);
    router_kernel<<<N_TOK / 64, 64, 0, stream>>>(x, rw, rb, counts, top1, psum, tk_e, tk_w);
    scan_kernel<<<1, 64, 0, stream>>>(counts, top1, psum, segOff, cursors, tileE, tileB,
                                      out + (size_t)N_TOK * D_IN);
    scatter_kernel<<<N_TOK / 64, 64, 0, stream>>>(tk_e, tk_w, cursors, rowTok, rowGate, pairPos);
    gather_kernel<<<NP, 192, 0, stream>>>(x, rowTok, Xg);
    ffn1_kernel<<<GRID1, 256, 0, stream>>>(Xg, W1T, W2T, b1, b2, Hb,
                                           tileE, tileB, segOff, counts);
    ffn2_kernel<<<GRID2, 512, 0, stream>>>(Hb, W3T, b3, rowGate, Yb,
                                           tileE, tileB, segOff, counts);
    combine_kernel<<<N_TOK, 192, 0, stream>>>(Yb, pairPos, out);
}